// Round 6
// baseline (111.907 us; speedup 1.0000x reference)
//
#include <hip/hip_runtime.h>

// ROIAlign: features (1, 256, 200, 200) f32, rois (N,4) f32 (y1,x1,y2,x2),
// img_size constant [800, 800]. Output (N, 256, 7, 7) f32.
//
// Pipeline:
//  0) roi_sort: bucket-sort ROIs by y-center into perm[] (one tiny block).
//  1) transpose_bf16: (C,H,W) f32 -> (H,W,C) bf16 in d_ws (round-5 kernel).
//  2) roialign_main5: block bid -> rank r = (bid%8)*64 + bid/8 -> n = perm[r].
//     With round-robin workgroup->XCD dispatch this gives each XCD a y-band
//     of co-resident ROIs (~9 MB footprint vs whole 20.5 MB map) -> higher L2
//     hit rate, less L2-miss traffic (the measured ~3.5 TB/s wall).

#define CCH 256
#define HF 200
#define WF 200
#define HOUT 7
#define WOUT 7
#define SPP 49
#define SPPP 50   // padded LDS stride

#define FT_BYTES ((size_t)HF * WF * CCH * sizeof(unsigned short))  // 20.48 MB

__device__ __forceinline__ unsigned short f2bf_rne(float x) {
    unsigned int u = __float_as_uint(x);
    unsigned int r = (u + 0x7fffu + ((u >> 16) & 1u)) >> 16;
    return (unsigned short)r;
}
__device__ __forceinline__ float bf_lo(unsigned int u) { return __uint_as_float(u << 16); }
__device__ __forceinline__ float bf_hi(unsigned int u) { return __uint_as_float(u & 0xffff0000u); }

// ---------------- ROI bucket-sort by y-center ----------------
// One block, 512 threads. perm[rank] = roi index; ranks ordered by 64-bucket
// y-center histogram (intra-bucket order arbitrary -- output is perm-invariant).
__global__ __launch_bounds__(512) void roi_sort(
    const float* __restrict__ rois, int* __restrict__ perm, int N)
{
    __shared__ int hist[64];
    __shared__ int base[64];
    int t = threadIdx.x;
    if (t < 64) hist[t] = 0;
    __syncthreads();

    for (int i = t; i < N; i += 512) {
        float yc = rois[i * 4 + 0] + rois[i * 4 + 2];   // 2*y-center, [0,1598]
        int b = (int)(yc * (64.0f / 1600.0f));
        b = min(63, max(0, b));
        atomicAdd(&hist[b], 1);
    }
    __syncthreads();
    if (t == 0) {
        int acc = 0;
        #pragma unroll
        for (int i = 0; i < 64; ++i) { base[i] = acc; acc += hist[i]; }
    }
    __syncthreads();
    for (int i = t; i < N; i += 512) {
        float yc = rois[i * 4 + 0] + rois[i * 4 + 2];
        int b = (int)(yc * (64.0f / 1600.0f));
        b = min(63, max(0, b));
        int old = atomicSub(&hist[b], 1);      // old in [1..count]
        perm[base[b] + old - 1] = i;
    }
}

// ---------------- transpose+quantize (C,H,W) f32 -> (H,W,C) bf16 -------------
__global__ __launch_bounds__(512) void transpose_bf16(
    const float* __restrict__ f,          // (C, H, W) f32
    unsigned short* __restrict__ ft)      // (H, W, C) bf16
{
    __shared__ unsigned short tile[64 * 256];   // 32 KB
    int h     = blockIdx.x;
    int wg    = blockIdx.y;
    int wbase = wg * 64;
    int t = threadIdx.x;
    int v  = t & 15;
    int cu = t >> 4;

    #pragma unroll
    for (int pass = 0; pass < 8; ++pass) {
        int c  = pass * 32 + cu;
        int w0 = wbase + 4 * v;
        if (w0 < WF) {
            float4 val = *(const float4*)&f[(size_t)c * (HF * WF) + (size_t)h * WF + w0];
            float vv[4] = {val.x, val.y, val.z, val.w};
            #pragma unroll
            for (int j = 0; j < 4; ++j) {
                int wl = 4 * v + j;
                int k  = (wl >> 2) & 7;
                tile[wl * 256 + (c ^ (k << 3))] = f2bf_rne(vv[j]);
            }
        }
    }
    __syncthreads();

    int l    = t & 63;
    int wave = t >> 6;
    int lc   = l & 31;
    #pragma unroll
    for (int p = 0; p < 4; ++p) {
        int wl = (p * 8 + wave) * 2 + (l >> 5);
        int w  = wbase + wl;
        int k  = (wl >> 2) & 7;
        int c8 = lc * 8;
        uint4 val = *(const uint4*)&tile[wl * 256 + (c8 ^ (k << 3))];
        if (w < WF) {
            *(uint4*)&ft[((size_t)h * WF + w) * CCH + c8] = val;
        }
    }
}

// ---------------- main v5: block = banded rank -> roi ----------------
__global__ __launch_bounds__(448, 4) void roialign_main5(
    const unsigned short* __restrict__ ft,   // (H, W, C) bf16
    const float* __restrict__ rois,          // (N, 4)
    const int* __restrict__ perm,            // (N,) y-sorted ranks
    float* __restrict__ out)                 // (N, C, 7, 7)
{
    __shared__ float smem[CCH * SPPP];   // 51.2 KB
    int bid = blockIdx.x;
    int G   = gridDim.x;
    int r   = bid;
    if ((G & 7) == 0) {                  // XCD banding: XCD k <- ranks [k*G/8, ...)
        int g = G >> 3;
        r = (bid & 7) * g + (bid >> 3);
    }
    int n = perm[r];

    int t  = threadIdx.x;
    int q  = t >> 6;        // wave -> ho
    int l  = t & 63;
    int al = l >> 5;        // subsample a
    int lc = l & 31;
    int c8 = lc * 8;        // channel base

    float r0 = (rois[n * 4 + 0] * 199.0f) / 799.0f;
    float r1 = (rois[n * 4 + 1] * 199.0f) / 799.0f;
    float r2 = (rois[n * 4 + 2] * 199.0f) / 799.0f;
    float r3 = (rois[n * 4 + 3] * 199.0f) / 799.0f;
    float h_step = (r2 - r0) / 14.0f;
    float w_step = (r3 - r1) / 14.0f;

    float yy = ((float)(2 * q + al) + 0.5f) * h_step + r0;
    float yf = floorf(yy);
    int   iu = (int)yf;
    int   id = (int)ceilf(yy);     // ceil, matches ref
    float fy = yy - yf;

    const unsigned short* rowu = ft + (size_t)iu * (WF * CCH) + c8;
    const unsigned short* rowd = ft + (size_t)id * (WF * CCH) + c8;

    #pragma unroll 1
    for (int wo = 0; wo < WOUT; ++wo) {
        float m[8];
        #pragma unroll
        for (int j = 0; j < 8; ++j) m[j] = -INFINITY;

        #pragma unroll
        for (int b = 0; b < 2; ++b) {
            float xx = ((float)(2 * wo + b) + 0.5f) * w_step + r1;
            float xf = floorf(xx);
            int   il = (int)xf;
            int   ir = (int)ceilf(xx);
            float fx = xx - xf;

            uint4 Uul = *(const uint4*)(rowu + (size_t)il * CCH);
            uint4 Uur = *(const uint4*)(rowu + (size_t)ir * CCH);
            uint4 Udl = *(const uint4*)(rowd + (size_t)il * CCH);
            uint4 Udr = *(const uint4*)(rowd + (size_t)ir * CCH);

            float w_ul = (1.0f - fy) * (1.0f - fx);
            float w_dl = fy * (1.0f - fx);
            float w_ur = (1.0f - fy) * fx;
            float w_dr = fy * fx;

            const unsigned int* pul = (const unsigned int*)&Uul;
            const unsigned int* pur = (const unsigned int*)&Uur;
            const unsigned int* pdl = (const unsigned int*)&Udl;
            const unsigned int* pdr = (const unsigned int*)&Udr;

            #pragma unroll
            for (int g = 0; g < 4; ++g) {
                float vlo = bf_lo(pul[g]) * w_ul + bf_lo(pdl[g]) * w_dl
                          + bf_lo(pur[g]) * w_ur + bf_lo(pdr[g]) * w_dr;
                float vhi = bf_hi(pul[g]) * w_ul + bf_hi(pdl[g]) * w_dl
                          + bf_hi(pur[g]) * w_ur + bf_hi(pdr[g]) * w_dr;
                m[2 * g + 0] = fmaxf(m[2 * g + 0], vlo);
                m[2 * g + 1] = fmaxf(m[2 * g + 1], vhi);
            }
        }

        #pragma unroll
        for (int j = 0; j < 8; ++j) m[j] = fmaxf(m[j], __shfl_xor(m[j], 32));

        if (al == 0) {
            int s = q * WOUT + wo;
            #pragma unroll
            for (int j = 0; j < 8; ++j) smem[(c8 + j) * SPPP + s] = m[j];
        }
    }
    __syncthreads();

    // flush: 256*49 floats, contiguous in out
    float* dst = out + (size_t)n * (CCH * SPP);
    #pragma unroll
    for (int p = 0; p < 7; ++p) {
        int o4 = p * 448 + t;
        int o  = o4 * 4;
        float tmp[4];
        #pragma unroll
        for (int i = 0; i < 4; ++i) {
            int oe = o + i;
            int c  = (int)((unsigned)oe / 49u);
            int s  = oe - c * 49;
            tmp[i] = smem[c * SPPP + s];
        }
        float4 rr;
        rr.x = tmp[0]; rr.y = tmp[1]; rr.z = tmp[2]; rr.w = tmp[3];
        *(float4*)&dst[o] = rr;
    }
}

// ---------------- fallback (no workspace) ----------------
__global__ __launch_bounds__(256) void roialign_fallback(
    const float* __restrict__ features,
    const float* __restrict__ rois,
    float* __restrict__ out,
    int total)
{
    int idx = blockIdx.x * blockDim.x + threadIdx.x;
    if (idx >= total) return;

    int s  = idx % SPP;
    int nc = idx / SPP;
    int c  = nc % CCH;
    int n  = nc / CCH;
    int ho = s / WOUT;
    int wo = s % WOUT;

    float r0 = (rois[n * 4 + 0] * 199.0f) / 799.0f;
    float r1 = (rois[n * 4 + 1] * 199.0f) / 799.0f;
    float r2 = (rois[n * 4 + 2] * 199.0f) / 799.0f;
    float r3 = (rois[n * 4 + 3] * 199.0f) / 799.0f;
    float h_step = (r2 - r0) / 14.0f;
    float w_step = (r3 - r1) / 14.0f;

    const float* fmap = features + (size_t)c * (HF * WF);
    float result = -INFINITY;

    #pragma unroll
    for (int a = 0; a < 2; ++a) {
        float yy = ((float)(2 * ho + a) + 0.5f) * h_step + r0;
        float yf = floorf(yy);
        int   iu = (int)yf;
        int   id = (int)ceilf(yy);
        float fy = yy - yf;
        const float* rowu = fmap + (size_t)iu * WF;
        const float* rowd = fmap + (size_t)id * WF;
        #pragma unroll
        for (int b = 0; b < 2; ++b) {
            float xx = ((float)(2 * wo + b) + 0.5f) * w_step + r1;
            float xf = floorf(xx);
            int   il = (int)xf;
            int   ir = (int)ceilf(xx);
            float fx = xx - xf;
            float val = rowu[il] * (1.0f - fy) * (1.0f - fx)
                      + rowd[il] * fy         * (1.0f - fx)
                      + rowu[ir] * (1.0f - fy) * fx
                      + rowd[ir] * fy         * fx;
            result = fmaxf(result, val);
        }
    }
    out[idx] = result;
}

extern "C" void kernel_launch(void* const* d_in, const int* in_sizes, int n_in,
                              void* d_out, int out_size, void* d_ws, size_t ws_size,
                              hipStream_t stream) {
    const float* features = (const float*)d_in[0];  // (1, 256, 200, 200)
    const float* rois     = (const float*)d_in[1];  // (N, 4)
    float* out = (float*)d_out;
    int N = in_sizes[1] / 4;

    const size_t need = FT_BYTES + (size_t)N * sizeof(int);
    if (ws_size >= need) {
        unsigned short* ft = (unsigned short*)d_ws;
        int* perm = (int*)((char*)d_ws + FT_BYTES);
        roi_sort<<<1, 512, 0, stream>>>(rois, perm, N);
        dim3 tgrid(HF, (WF + 63) / 64);
        transpose_bf16<<<tgrid, 512, 0, stream>>>(features, ft);
        roialign_main5<<<N, 448, 0, stream>>>(ft, rois, perm, out);
    } else {
        int total = N * CCH * SPP;
        roialign_fallback<<<(total + 255) / 256, 256, 0, stream>>>(features, rois, out, total);
    }
}